// Round 1
// baseline (1435.286 us; speedup 1.0000x reference)
//
#include <hip/hip_runtime.h>
#include <hip/hip_bf16.h>
#include <stdint.h>

// Problem constants
#define B_SZ   4096
#define F_SZ   40960
#define M_SZ   256
#define KSPLIT 4
#define KSLICE (F_SZ / KSPLIT)   // 10240
#define BK     64
#define NCHUNK (KSLICE / BK)     // 160

typedef float    f32x4  __attribute__((ext_vector_type(4)));
typedef float    f32x8  __attribute__((ext_vector_type(8)));
typedef __bf16   bf16x4 __attribute__((ext_vector_type(4)));
typedef __bf16   bf16x8 __attribute__((ext_vector_type(8)));

// ws layout: [0, 20971520): ft_w as bf16 [256][40960], 16B-slot XOR-swizzled
//            [20971520, 54525952): split-K partials float [KSPLIT][4096][512]
#define WS_WBF_BYTES ((size_t)M_SZ * F_SZ * 2)

// global -> LDS DMA, 16B per lane. LDS dest must be linear (wave base + lane*16).
typedef const __attribute__((address_space(1))) unsigned int* gas_ptr;
typedef __attribute__((address_space(3))) unsigned int*       las_ptr;
__device__ __forceinline__ void gload_lds16(const void* g, void* l) {
    __builtin_amdgcn_global_load_lds((gas_ptr)g, (las_ptr)l, 16, 0, 0);
}

// ---------------------------------------------------------------------------
// Kernel 0: ft_w fp32 -> bf16, PRE-SWIZZLED.
// Within each aligned 64-col block (8 x 16B slots), slot s of row m is stored
// at slot s ^ (m&7). k_ftgemm copies rows linearly into LDS via
// global_load_lds (which cannot scatter), and its ds_read_b128 fragment reads
// apply the same XOR -> bank-conflict-free (2 lanes/bank = free, m136).
// ---------------------------------------------------------------------------
__global__ __launch_bounds__(256) void k_wcvt(const float* __restrict__ src,
                                              __bf16* __restrict__ dst) {
    unsigned i = ((unsigned)blockIdx.x * 256 + threadIdx.x) * 8;
    unsigned m   = i / F_SZ;
    unsigned rem = i - m * F_SZ;
    unsigned slot = (rem >> 3) & 7;
    unsigned drem = (rem & ~63u) | ((slot ^ (m & 7)) << 3);
    f32x8 a = *(const f32x8*)(src + i);
    bf16x8 o = __builtin_convertvector(a, bf16x8);
    *(bf16x8*)(dst + (size_t)m * F_SZ + drem) = o;
}

// ---------------------------------------------------------------------------
// Kernel 1: feature-transformer GEMM.
// Tile: 64 A-rows (one perspective strip) x 256 cols (all of M), K-slice of
// 10240 per blockIdx.y. Grid (128, 4) = 512 blocks of 256 threads (4 waves)
// -> 2 blocks/CU (LDS 73728 B/block): two independent barrier domains per CU
// interleave, so one block's vmcnt drain overlaps the other's issue/MFMA.
// W is staged by global_load_lds (double-buffered, pure DMA, no VGPRs);
// A is reg-prefetched + cvt'd to bf16 into a single swizzled buffer.
// Wave wv owns cols [wv*64, wv*64+64) over all 64 rows (4x4 16x16 frags).
// ---------------------------------------------------------------------------
__global__ __launch_bounds__(256, 2) void k_ftgemm(
    const float* __restrict__ white, const float* __restrict__ black,
    const __bf16* __restrict__ wbf, float* __restrict__ part)
{
    __shared__ __bf16 Abuf[64 * 64];          //  8 KB, swizzled 16B slots
    __shared__ __bf16 Wbuf[2][M_SZ * 64];     // 64 KB, swizzled 16B slots

    const int tid   = threadIdx.x;
    const int bx    = blockIdx.x;            // 0..127
    const int persp = bx >> 6;               // 0 = white rows, 1 = black rows
    const int r0    = (bx & 63) * 64;        // batch row base
    const int kbase = blockIdx.y * KSLICE;

    const float* abase = persp ? black : white;

    // A staging: row arw = tid>>2, 16 consecutive floats at col (tid&3)*16
    const int arw = tid >> 2;
    const int as0 = (tid & 3) * 2;           // first 16B slot index
    const float* aP = abase + (size_t)(r0 + arw) * F_SZ + kbase + (tid & 3) * 16;
    char* aW0 = (char*)Abuf + arw * 128 + (((as0    ) ^ (arw & 7)) << 4);
    char* aW1 = (char*)Abuf + arw * 128 + (((as0 + 1) ^ (arw & 7)) << 4);

    // W staging (global_load_lds): call c covers rows [c*32, c*32+32);
    // thread -> row c*32 + (tid>>3), slot tid&7. Source is pre-swizzled, so a
    // straight linear copy lands the swizzled image in LDS.
    const __bf16* wPg = wbf + (size_t)(tid >> 3) * F_SZ + kbase + (tid & 7) * 8;

    f32x8 areg[2];

    auto load_A = [&](int kc) {
        const float* p = aP + kc * BK;
        areg[0] = *(const f32x8*)(p);
        areg[1] = *(const f32x8*)(p + 8);
    };
    auto write_A = [&]() {
        bf16x8 v0 = __builtin_convertvector(areg[0], bf16x8);
        bf16x8 v1 = __builtin_convertvector(areg[1], bf16x8);
        *(bf16x8*)aW0 = v0;
        *(bf16x8*)aW1 = v1;
    };
    auto stage_W = [&](int kc, int buf) {
        const __bf16* g = wPg + kc * BK;
        char* l = (char*)&Wbuf[buf][0] + tid * 16;
#pragma unroll
        for (int c = 0; c < 8; ++c)
            gload_lds16(g + (size_t)c * 32 * F_SZ, l + c * 4096);
    };

    // MFMA mapping
    const int lane = tid & 63;
    const int wv   = tid >> 6;          // 0..3
    const int m0   = wv * 64;           // col block
    const int lr   = lane & 15;
    const int q    = lane >> 4;

    // swizzled 16B-slot offsets: kst=0 -> slots 0..3 (q), kst=1 -> 4..7 (q|4)
    const int sw0 = (((q    ) ^ (lr & 7)) << 4);
    const int sw1 = (((q | 4) ^ (lr & 7)) << 4);

    const char* aR  = (const char*)Abuf + lr * 128;
    const char* wR0 = (const char*)&Wbuf[0][0] + (m0 + lr) * 128;
    const char* wR1 = (const char*)&Wbuf[1][0] + (m0 + lr) * 128;

    f32x4 acc[4][4];
#pragma unroll
    for (int r = 0; r < 4; ++r)
#pragma unroll
        for (int c = 0; c < 4; ++c) acc[r][c] = (f32x4){0.f, 0.f, 0.f, 0.f};

    stage_W(0, 0);     // W(0) issued BEFORE A(0): areg wait implies W landed
    load_A(0);

    for (int kc = 0; kc < NCHUNK; ++kc) {
        __syncthreads();                 // full vmcnt drain: prefetches landed,
        write_A();                       //   prev readers done
        __syncthreads();
        if (kc + 1 < NCHUNK) {           // prefetch next chunk during MFMA
            stage_W(kc + 1, (kc + 1) & 1);
            load_A(kc + 1);
        }
        const char* wR = (kc & 1) ? wR1 : wR0;
#pragma unroll
        for (int kst = 0; kst < 2; ++kst) {
            const int swk = kst ? sw1 : sw0;
            bf16x8 af[4], wf[4];
#pragma unroll
            for (int r = 0; r < 4; ++r)
                af[r] = *(const bf16x8*)(aR + r * 2048 + swk);
#pragma unroll
            for (int c = 0; c < 4; ++c)
                wf[c] = *(const bf16x8*)(wR + c * 2048 + swk);
#pragma unroll
            for (int r = 0; r < 4; ++r)
#pragma unroll
                for (int c = 0; c < 4; ++c)
                    acc[r][c] = __builtin_amdgcn_mfma_f32_16x16x32_bf16(
                        af[r], wf[c], acc[r][c], 0, 0, 0);
        }
    }

    // epilogue: C/D layout col=lane&15, row=q*4+e (same convention as before)
    float* pb = part + (size_t)blockIdx.y * ((size_t)B_SZ * 512)
              + (size_t)r0 * 512 + persp * 256 + m0;
#pragma unroll
    for (int r = 0; r < 4; ++r)
#pragma unroll
        for (int e = 0; e < 4; ++e) {
            const int row = r * 16 + q * 4 + e;
#pragma unroll
            for (int c = 0; c < 4; ++c)
                pb[(size_t)row * 512 + c * 16 + lr] = acc[r][c][e];
        }
}

// ---------------------------------------------------------------------------
// Kernel 2: split-K reduce + bias + clip + stm-select, then l1/l2 head (fp32).
// One wave per batch row; 4 rows per 256-thread block.
// ---------------------------------------------------------------------------
__global__ __launch_bounds__(256) void k_head(
    const float* __restrict__ part, const float* __restrict__ stm,
    const float* __restrict__ ftb,  const float* __restrict__ l1w,
    const float* __restrict__ l1b,  const float* __restrict__ l2w,
    const float* __restrict__ l2b,  float* __restrict__ out)
{
    __shared__ float xs[4][512];
    const int wv   = threadIdx.x >> 6;
    const int lane = threadIdx.x & 63;
    const int i    = blockIdx.x * 4 + wv;

    const int swap = (stm[i] == 0.0f) ? 256 : 0;   // stm==0 -> [b, w]

#pragma unroll
    for (int t = 0; t < 8; ++t) {
        const int j   = t * 64 + lane;
        const int col = (j + swap) & 511;
        float v = 0.f;
#pragma unroll
        for (int s = 0; s < KSPLIT; ++s)
            v += part[(size_t)s * B_SZ * 512 + (size_t)i * 512 + col];
        v += ftb[j & 255];
        v = fminf(fmaxf(v, 0.f), 1.f);
        xs[wv][j] = v;
    }
    __syncthreads();

    // l1: lane = (n in 0..31, h in 0..1); each lane does 256 MACs (float4)
    const int n = lane & 31;
    const int h = lane >> 5;
    float a = 0.f;
    const float* wrow = l1w + n * 512 + h * 256;
    const float* xrow = &xs[wv][h * 256];
#pragma unroll 8
    for (int jj = 0; jj < 256; jj += 4) {
        f32x4 xv  = *(const f32x4*)(xrow + jj);
        f32x4 wv4 = *(const f32x4*)(wrow + jj);
        a += xv.x * wv4.x + xv.y * wv4.y + xv.z * wv4.z + xv.w * wv4.w;
    }
    a += __shfl_xor(a, 32);                 // combine halves
    float y = fminf(fmaxf(a + l1b[n], 0.f), 1.f);

    float p = (h == 0) ? y * l2w[n] : 0.f;  // l2 dot over 32 outputs
#pragma unroll
    for (int off = 16; off >= 1; off >>= 1) p += __shfl_xor(p, off);
    if (lane == 0) out[i] = p + l2b[0];
}

// ---------------------------------------------------------------------------
extern "C" void kernel_launch(void* const* d_in, const int* in_sizes, int n_in,
                              void* d_out, int out_size, void* d_ws, size_t ws_size,
                              hipStream_t stream) {
    (void)in_sizes; (void)n_in; (void)out_size; (void)ws_size;
    const float* white = (const float*)d_in[0];
    const float* black = (const float*)d_in[1];
    const float* stm   = (const float*)d_in[2];
    const float* ftw   = (const float*)d_in[3];
    const float* ftb   = (const float*)d_in[4];
    const float* l1w   = (const float*)d_in[5];
    const float* l1b   = (const float*)d_in[6];
    const float* l2w   = (const float*)d_in[7];
    const float* l2b   = (const float*)d_in[8];

    __bf16* wbf  = (__bf16*)d_ws;                             // 20.97 MB
    float*  part = (float*)((char*)d_ws + WS_WBF_BYTES);      // 33.55 MB

    hipLaunchKernelGGL(k_wcvt, dim3((M_SZ * F_SZ) / (256 * 8)), dim3(256), 0, stream,
                       ftw, wbf);
    hipLaunchKernelGGL(k_ftgemm, dim3(128, KSPLIT), dim3(256), 0, stream,
                       white, black, wbf, part);
    hipLaunchKernelGGL(k_head, dim3(B_SZ / 4), dim3(256), 0, stream,
                       part, stm, ftb, l1w, l1b, l2w, l2b, (float*)d_out);
}